// Round 1
// baseline (1270.522 us; speedup 1.0000x reference)
//
#include <hip/hip_runtime.h>
#include <stdint.h>

#define T_TOKENS 8192
#define D_DIM 1024
#define I_DIM 2816
#define E_NUM 16
#define N_SLOTS 16384

typedef float f32x4 __attribute__((ext_vector_type(4)));
typedef short s16x8 __attribute__((ext_vector_type(8)));
typedef short s16x4 __attribute__((ext_vector_type(4)));
typedef unsigned short u16;
typedef unsigned int u32;

__device__ __forceinline__ u16 f2bf(float f) {
  u32 u = __builtin_bit_cast(u32, f);
  u = (u + 0x7FFFu + ((u >> 16) & 1u)) >> 16;
  return (u16)u;
}
__device__ __forceinline__ float bf2f(u16 h) {
  u32 u = ((u32)h) << 16;
  return __builtin_bit_cast(float, u);
}
__device__ __forceinline__ u32 pack2(float a, float b) {
  return (u32)f2bf(a) | ((u32)f2bf(b) << 16);
}
__device__ __forceinline__ void async_load16(const void* g, void* l) {
  __builtin_amdgcn_global_load_lds(
      (const __attribute__((address_space(1))) void*)g,
      (__attribute__((address_space(3))) void*)l, 16, 0, 0);
}

// ---------------- router: logits -> softmax -> top2 -> weights ----------------
__global__ void router_kernel(const float* __restrict__ x,
                              const float* __restrict__ gw,
                              int* __restrict__ e12, float* __restrict__ w12,
                              int* __restrict__ cnt, float* __restrict__ probsum) {
  __shared__ float sProb[E_NUM];
  __shared__ int sCnt[E_NUM];
  int tid = threadIdx.x;
  if (tid < E_NUM) { sProb[tid] = 0.f; sCnt[tid] = 0; }
  __syncthreads();
  int g = tid >> 4, i = tid & 15;
  int t = blockIdx.x * 16 + g;
  float acc[E_NUM];
#pragma unroll
  for (int e = 0; e < E_NUM; e++) acc[e] = 0.f;
  const f32x4* x4 = (const f32x4*)(x + (size_t)t * D_DIM);
  const f32x4* g4 = (const f32x4*)gw;
  for (int jj = 0; jj < 16; jj++) {
    f32x4 xv = x4[i + 16 * jj];
    int jb = 4 * (i + 16 * jj);
#pragma unroll
    for (int r = 0; r < 4; r++) {
      float xs = xv[r];
#pragma unroll
      for (int e4 = 0; e4 < 4; e4++) {
        f32x4 gv = g4[(jb + r) * 4 + e4];
        acc[e4 * 4 + 0] += xs * gv[0];
        acc[e4 * 4 + 1] += xs * gv[1];
        acc[e4 * 4 + 2] += xs * gv[2];
        acc[e4 * 4 + 3] += xs * gv[3];
      }
    }
  }
#pragma unroll
  for (int e = 0; e < E_NUM; e++) {
    float v = acc[e];
    v += __shfl_down(v, 8, 16);
    v += __shfl_down(v, 4, 16);
    v += __shfl_down(v, 2, 16);
    v += __shfl_down(v, 1, 16);
    acc[e] = v;
  }
  if (i == 0) {
    float mx = acc[0];
#pragma unroll
    for (int e = 1; e < E_NUM; e++) mx = fmaxf(mx, acc[e]);
    float p[E_NUM]; float s = 0.f;
#pragma unroll
    for (int e = 0; e < E_NUM; e++) { p[e] = __expf(acc[e] - mx); s += p[e]; }
    float inv = 1.f / s;
#pragma unroll
    for (int e = 0; e < E_NUM; e++) p[e] *= inv;
    int e1 = 0; float p1 = p[0];
#pragma unroll
    for (int e = 1; e < E_NUM; e++) if (p[e] > p1) { p1 = p[e]; e1 = e; }
    int e2 = (e1 == 0) ? 1 : 0; float p2 = p[e2];
#pragma unroll
    for (int e = 0; e < E_NUM; e++) if (e != e1 && p[e] > p2) { p2 = p[e]; e2 = e; }
    float wsum = p1 + p2;
    e12[2 * t] = e1; e12[2 * t + 1] = e2;
    w12[2 * t] = p1 / wsum; w12[2 * t + 1] = p2 / wsum;
#pragma unroll
    for (int e = 0; e < E_NUM; e++) atomicAdd(&sProb[e], p[e]);
    atomicAdd(&sCnt[e1], 1);
    atomicAdd(&sCnt[e2], 1);
  }
  __syncthreads();
  if (tid < E_NUM) {
    atomicAdd(&cnt[tid], sCnt[tid]);
    atomicAdd(&probsum[tid], sProb[tid]);
  }
}

__global__ void prefix_kernel(const int* __restrict__ cnt, int* __restrict__ offsets) {
  if (threadIdx.x == 0) {
    int s = 0;
    for (int e = 0; e < E_NUM; e++) { offsets[e] = s; s += cnt[e]; }
    offsets[E_NUM] = s;
  }
}

__global__ void build_kernel(const int* __restrict__ e12, const float* __restrict__ w12,
                             const int* __restrict__ offsets, int* __restrict__ cursor,
                             int* __restrict__ tlist, float* __restrict__ wlist) {
  int t = blockIdx.x * 256 + threadIdx.x;
  if (t >= T_TOKENS) return;
#pragma unroll
  for (int k = 0; k < 2; k++) {
    int e = e12[2 * t + k];
    int pos = atomicAdd(&cursor[e], 1);
    int idx = offsets[e] + pos;
    tlist[idx] = t;
    wlist[idx] = w12[2 * t + k];
  }
}

__global__ void gather_kernel(const float* __restrict__ x, const int* __restrict__ tlist,
                              u16* __restrict__ Xe) {
  int r = blockIdx.x * 4 + (threadIdx.x >> 6);
  int lane = threadIdx.x & 63;
  int tok = tlist[r];
  const f32x4* src = (const f32x4*)(x + (size_t)tok * D_DIM);
  u32* dst = (u32*)(Xe + (size_t)r * D_DIM);
#pragma unroll
  for (int c = 0; c < 4; c++) {
    f32x4 v = src[lane + 64 * c];
    dst[(lane + 64 * c) * 2] = pack2(v[0], v[1]);
    dst[(lane + 64 * c) * 2 + 1] = pack2(v[2], v[3]);
  }
}

// ---------------- grouped GEMM, 128x128 tile, bf16 MFMA 16x16x32 ----------------
// MODE 0: G = silu(Xe @ Wg)          -> Hbuf (bf16)
// MODE 1: U = Xe @ Wu; H = G * U     -> Hbuf (rmw)
// MODE 2: out[tok] += w * (H @ Wd)   (fp32 atomicAdd)
template <int MODE, int KDIM, int NDIM>
__global__ __launch_bounds__(256) void gemm_kernel(
    const u16* __restrict__ Abuf, const float* __restrict__ Bw,
    u16* __restrict__ Hbuf, float* __restrict__ out,
    const int* __restrict__ cnt, const int* __restrict__ offsets,
    const int* __restrict__ tlist, const float* __restrict__ wlist) {
  int e = blockIdx.z;
  int Me = cnt[e];
  int m0 = blockIdx.y * 128;
  if (m0 >= Me) return;
  int n0 = blockIdx.x * 128;
  int rowBase = offsets[e];
  const float* Be = Bw + (size_t)e * KDIM * NDIM;

  __shared__ u16 Ash[128 * 32];   // [row][k] row-major, 64B rows
  __shared__ u16 Bsh[128 * 36];   // [n][k] transposed, +4 pad (72B stride)

  int tid = threadIdx.x;
  int lane = tid & 63;
  int wv = tid >> 6;
  int mq = wv & 1, nq = wv >> 1;
  int lrow = lane & 15, lq = lane >> 4;
  int tmod = tid & 31, tdiv = tid >> 5;

  f32x4 acc[4][4];
#pragma unroll
  for (int a = 0; a < 4; a++)
#pragma unroll
    for (int b = 0; b < 4; b++) acc[a][b] = (f32x4)0.f;

  for (int k0 = 0; k0 < KDIM; k0 += 32) {
    // A tile: 128 rows x 32 bf16 via global_load_lds width 16
#pragma unroll
    for (int rep = 0; rep < 2; rep++) {
      int idx = tid + 256 * rep;
      int row = idx >> 2, q = idx & 3;
      int gr = m0 + row;
      gr = (gr < Me) ? gr : (Me - 1);  // clamp; masked at epilogue
      const u16* gsrc = Abuf + (size_t)(rowBase + gr) * KDIM + k0 + q * 8;
      async_load16(gsrc, &Ash[(wv * 64 + 256 * rep) * 8]);
    }
    // B tile: 32(k) x 128(n) fp32 -> bf16 transposed [n][k]
#pragma unroll
    for (int rep = 0; rep < 2; rep++) {
      int k = 2 * (tdiv + rep * 8);
      const float* b0 = Be + (size_t)(k0 + k) * NDIM + n0;
      const float* b1 = b0 + NDIM;
#pragma unroll
      for (int ii = 0; ii < 4; ii++) {
        int n = tmod + ii * 32;
        *(u32*)&Bsh[n * 36 + k] = pack2(b0[n], b1[n]);
      }
    }
    __syncthreads();
    s16x8 af[4], bfr[4];
#pragma unroll
    for (int fm = 0; fm < 4; fm++)
      af[fm] = *(const s16x8*)&Ash[(mq * 64 + fm * 16 + lrow) * 32 + lq * 8];
#pragma unroll
    for (int fn = 0; fn < 4; fn++) {
      const u16* bp = &Bsh[(nq * 64 + fn * 16 + lrow) * 36 + lq * 8];
      s16x4 lo = *(const s16x4*)bp;
      s16x4 hi = *(const s16x4*)(bp + 4);
      bfr[fn] = __builtin_shufflevector(lo, hi, 0, 1, 2, 3, 4, 5, 6, 7);
    }
#pragma unroll
    for (int fm = 0; fm < 4; fm++)
#pragma unroll
      for (int fn = 0; fn < 4; fn++)
        acc[fm][fn] = __builtin_amdgcn_mfma_f32_16x16x32_bf16(af[fm], bfr[fn], acc[fm][fn], 0, 0, 0);
    __syncthreads();
  }
  // epilogue: C/D layout col=lane&15, row=(lane>>4)*4+reg  [m89-verified]
#pragma unroll
  for (int fm = 0; fm < 4; fm++) {
#pragma unroll
    for (int i = 0; i < 4; i++) {
      int m = m0 + mq * 64 + fm * 16 + lq * 4 + i;
      if (m >= Me) continue;
      size_t arow = (size_t)(rowBase + m);
#pragma unroll
      for (int fn = 0; fn < 4; fn++) {
        int col = n0 + nq * 64 + fn * 16 + lrow;
        float v = acc[fm][fn][i];
        if (MODE == 0) {
          float sg = v / (1.f + __expf(-v));
          Hbuf[arow * I_DIM + col] = f2bf(sg);
        } else if (MODE == 1) {
          size_t hx = arow * I_DIM + col;
          float gg = bf2f(Hbuf[hx]);
          Hbuf[hx] = f2bf(gg * v);
        } else {
          int tok = tlist[arow];
          float w = wlist[arow];
          atomicAdd(&out[(size_t)tok * D_DIM + col], v * w);
        }
      }
    }
  }
}

__global__ void aux_kernel(const int* __restrict__ cnt, const float* __restrict__ probsum,
                           float* __restrict__ aux_out) {
  if (threadIdx.x == 0) {
    float s = 0.f;
    for (int e = 0; e < E_NUM; e++) s += (float)cnt[e] * probsum[e];
    aux_out[0] = 0.01f * 16.f * s / (8192.f * 8192.f);
  }
}

// ws layout (bytes):
//   0: cnt[16] | 64: cursor[16] | 128: probsum[16] | 192: offsets[17]
//   512: e12[16384] int | 66048: w12[16384] f32
//   131584: tlist[16384] int | 197120: wlist[16384] f32
//   1MiB: Xe bf16 [16384][1024]  (32 MiB)
//   34603008: H bf16 [16384][2816] (88 MiB)   total ~121 MiB
extern "C" void kernel_launch(void* const* d_in, const int* in_sizes, int n_in,
                              void* d_out, int out_size, void* d_ws, size_t ws_size,
                              hipStream_t stream) {
  const float* x  = (const float*)d_in[0];
  const float* gw = (const float*)d_in[1];
  const float* Wg = (const float*)d_in[2];
  const float* Wu = (const float*)d_in[3];
  const float* Wd = (const float*)d_in[4];
  float* outf = (float*)d_out;
  char* ws = (char*)d_ws;
  int*   cnt     = (int*)(ws + 0);
  int*   cursor  = (int*)(ws + 64);
  float* probsum = (float*)(ws + 128);
  int*   offsets = (int*)(ws + 192);
  int*   e12     = (int*)(ws + 512);
  float* w12     = (float*)(ws + 66048);
  int*   tlist   = (int*)(ws + 131584);
  float* wlist   = (float*)(ws + 197120);
  u16*   Xe      = (u16*)(ws + (1 << 20));
  u16*   H       = (u16*)(ws + 34603008);

  hipMemsetAsync(d_out, 0, (size_t)(T_TOKENS * D_DIM + 1) * sizeof(float), stream);
  hipMemsetAsync(d_ws, 0, 512, stream);

  router_kernel<<<512, 256, 0, stream>>>(x, gw, e12, w12, cnt, probsum);
  prefix_kernel<<<1, 64, 0, stream>>>(cnt, offsets);
  build_kernel<<<32, 256, 0, stream>>>(e12, w12, offsets, cursor, tlist, wlist);
  gather_kernel<<<4096, 256, 0, stream>>>(x, tlist, Xe);

  gemm_kernel<0, D_DIM, I_DIM><<<dim3(22, 64, E_NUM), 256, 0, stream>>>(
      Xe, Wg, H, outf, cnt, offsets, tlist, wlist);
  gemm_kernel<1, D_DIM, I_DIM><<<dim3(22, 64, E_NUM), 256, 0, stream>>>(
      Xe, Wu, H, outf, cnt, offsets, tlist, wlist);
  gemm_kernel<2, I_DIM, D_DIM><<<dim3(8, 64, E_NUM), 256, 0, stream>>>(
      H, Wd, H, outf, cnt, offsets, tlist, wlist);

  aux_kernel<<<1, 64, 0, stream>>>(cnt, probsum, outf + (size_t)(T_TOKENS * D_DIM));
}

// Round 2
// 1131.595 us; speedup vs baseline: 1.1228x; 1.1228x over previous
//
#include <hip/hip_runtime.h>
#include <stdint.h>

#define T_TOKENS 8192
#define D_DIM 1024
#define I_DIM 2816
#define E_NUM 16
#define N_SLOTS 16384

typedef float f32x4 __attribute__((ext_vector_type(4)));
typedef short s16x8 __attribute__((ext_vector_type(8)));
typedef short s16x4 __attribute__((ext_vector_type(4)));
typedef unsigned short u16;
typedef unsigned int u32;

__device__ __forceinline__ u16 f2bf(float f) {
  u32 u = __builtin_bit_cast(u32, f);
  u = (u + 0x7FFFu + ((u >> 16) & 1u)) >> 16;
  return (u16)u;
}
__device__ __forceinline__ u32 pack2(float a, float b) {
  return (u32)f2bf(a) | ((u32)f2bf(b) << 16);
}
__device__ __forceinline__ void async_load16(const void* g, void* l) {
  __builtin_amdgcn_global_load_lds(
      (const __attribute__((address_space(1))) void*)g,
      (__attribute__((address_space(3))) void*)l, 16, 0, 0);
}

// ---------------- router: logits -> softmax -> top2 -> weights ----------------
__global__ void router_kernel(const float* __restrict__ x,
                              const float* __restrict__ gw,
                              int* __restrict__ e12, float* __restrict__ w12,
                              int* __restrict__ cnt, float* __restrict__ probsum) {
  __shared__ float sProb[E_NUM];
  __shared__ int sCnt[E_NUM];
  int tid = threadIdx.x;
  if (tid < E_NUM) { sProb[tid] = 0.f; sCnt[tid] = 0; }
  __syncthreads();
  int g = tid >> 4, i = tid & 15;
  int t = blockIdx.x * 16 + g;
  float acc[E_NUM];
#pragma unroll
  for (int e = 0; e < E_NUM; e++) acc[e] = 0.f;
  const f32x4* x4 = (const f32x4*)(x + (size_t)t * D_DIM);
  const f32x4* g4 = (const f32x4*)gw;
  for (int jj = 0; jj < 16; jj++) {
    f32x4 xv = x4[i + 16 * jj];
    int jb = 4 * (i + 16 * jj);
#pragma unroll
    for (int r = 0; r < 4; r++) {
      float xs = xv[r];
#pragma unroll
      for (int e4 = 0; e4 < 4; e4++) {
        f32x4 gv = g4[(jb + r) * 4 + e4];
        acc[e4 * 4 + 0] += xs * gv[0];
        acc[e4 * 4 + 1] += xs * gv[1];
        acc[e4 * 4 + 2] += xs * gv[2];
        acc[e4 * 4 + 3] += xs * gv[3];
      }
    }
  }
#pragma unroll
  for (int e = 0; e < E_NUM; e++) {
    float v = acc[e];
    v += __shfl_down(v, 8, 16);
    v += __shfl_down(v, 4, 16);
    v += __shfl_down(v, 2, 16);
    v += __shfl_down(v, 1, 16);
    acc[e] = v;
  }
  if (i == 0) {
    float mx = acc[0];
#pragma unroll
    for (int e = 1; e < E_NUM; e++) mx = fmaxf(mx, acc[e]);
    float p[E_NUM]; float s = 0.f;
#pragma unroll
    for (int e = 0; e < E_NUM; e++) { p[e] = __expf(acc[e] - mx); s += p[e]; }
    float inv = 1.f / s;
#pragma unroll
    for (int e = 0; e < E_NUM; e++) p[e] *= inv;
    int e1 = 0; float p1 = p[0];
#pragma unroll
    for (int e = 1; e < E_NUM; e++) if (p[e] > p1) { p1 = p[e]; e1 = e; }
    int e2 = (e1 == 0) ? 1 : 0; float p2 = p[e2];
#pragma unroll
    for (int e = 0; e < E_NUM; e++) if (e != e1 && p[e] > p2) { p2 = p[e]; e2 = e; }
    float wsum = p1 + p2;
    e12[2 * t] = e1; e12[2 * t + 1] = e2;
    w12[2 * t] = p1 / wsum; w12[2 * t + 1] = p2 / wsum;
#pragma unroll
    for (int e = 0; e < E_NUM; e++) atomicAdd(&sProb[e], p[e]);
    atomicAdd(&sCnt[e1], 1);
    atomicAdd(&sCnt[e2], 1);
  }
  __syncthreads();
  if (tid < E_NUM) {
    atomicAdd(&cnt[tid], sCnt[tid]);
    atomicAdd(&probsum[tid], sProb[tid]);
  }
}

__global__ void prefix_kernel(const int* __restrict__ cnt, int* __restrict__ offsets,
                              const float* __restrict__ probsum, float* __restrict__ aux_out) {
  if (threadIdx.x == 0) {
    int s = 0;
    for (int e = 0; e < E_NUM; e++) { offsets[e] = s; s += cnt[e]; }
    offsets[E_NUM] = s;
    float a = 0.f;
    for (int e = 0; e < E_NUM; e++) a += (float)cnt[e] * probsum[e];
    aux_out[0] = 0.01f * 16.f * a / (8192.f * 8192.f);
  }
}

__global__ void build_kernel(const int* __restrict__ e12, const float* __restrict__ w12,
                             const int* __restrict__ offsets, int* __restrict__ cursor,
                             int* __restrict__ tlist, float* __restrict__ wlist) {
  int t = blockIdx.x * 256 + threadIdx.x;
  if (t >= T_TOKENS) return;
#pragma unroll
  for (int k = 0; k < 2; k++) {
    int e = e12[2 * t + k];
    int pos = atomicAdd(&cursor[e], 1);
    int idx = offsets[e] + pos;
    tlist[idx] = t;
    wlist[idx] = w12[2 * t + k];
  }
}

__global__ void gather_kernel(const float* __restrict__ x, const int* __restrict__ tlist,
                              u16* __restrict__ Xe) {
  int r = blockIdx.x * 4 + (threadIdx.x >> 6);
  int lane = threadIdx.x & 63;
  int tok = tlist[r];
  const f32x4* src = (const f32x4*)(x + (size_t)tok * D_DIM);
  u32* dst = (u32*)(Xe + (size_t)r * D_DIM);
#pragma unroll
  for (int c = 0; c < 4; c++) {
    f32x4 v = src[lane + 64 * c];
    dst[(lane + 64 * c) * 2] = pack2(v[0], v[1]);
    dst[(lane + 64 * c) * 2 + 1] = pack2(v[2], v[3]);
  }
}

// ------------- weight transpose+convert: fp32 [E][K][N] -> bf16 [E][N][K] -------------
template <int K, int N>
__global__ __launch_bounds__(256) void transpose_kernel(const float* __restrict__ W,
                                                        u16* __restrict__ Wt) {
  __shared__ u16 tile[64][66];  // stride 66 shorts = 33 dwords -> bank-friendly
  int e = blockIdx.z;
  int k0 = blockIdx.x * 64;
  int n0 = blockIdx.y * 64;
  const float* Win = W + (size_t)e * K * N;
  u16* Wout = Wt + (size_t)e * N * K;
  int t = threadIdx.x;
  int r = t >> 4;          // 0..15
  int c4 = (t & 15) * 4;   // 0..60
#pragma unroll
  for (int rep = 0; rep < 4; rep++) {
    int k = r + rep * 16;
    f32x4 v = *(const f32x4*)(Win + (size_t)(k0 + k) * N + n0 + c4);
    *(u32*)&tile[k][c4] = pack2(v[0], v[1]);
    *(u32*)&tile[k][c4 + 2] = pack2(v[2], v[3]);
  }
  __syncthreads();
#pragma unroll
  for (int rep = 0; rep < 4; rep++) {
    int n = r + rep * 16;
    int k4 = c4;
    s16x4 o;
    o[0] = tile[k4 + 0][n];
    o[1] = tile[k4 + 1][n];
    o[2] = tile[k4 + 2][n];
    o[3] = tile[k4 + 3][n];
    *(s16x4*)(Wout + (size_t)(n0 + n) * K + k0 + k4) = o;
  }
}

// ------- fused G/U GEMM: H = silu(Xe@WgT) * (Xe@WuT), 128x128 tile, bf16 MFMA -------
__global__ __launch_bounds__(256, 2) void gemm_gu_kernel(
    const u16* __restrict__ Abuf, const u16* __restrict__ Bg, const u16* __restrict__ Bu,
    u16* __restrict__ Hbuf,
    const int* __restrict__ cnt, const int* __restrict__ offsets) {
  int e = blockIdx.z;
  int Me = cnt[e];
  int m0 = blockIdx.y * 128;
  if (m0 >= Me) return;
  int n0 = blockIdx.x * 128;
  int rowBase = offsets[e];
  const u16* Bge = Bg + (size_t)e * I_DIM * D_DIM;
  const u16* Bue = Bu + (size_t)e * I_DIM * D_DIM;

  __shared__ u16 Ash[128 * 32];
  __shared__ u16 Bgsh[128 * 32];
  __shared__ u16 Bush[128 * 32];

  int tid = threadIdx.x;
  int lane = tid & 63;
  int wv = tid >> 6;
  int mq = wv & 1, nq = wv >> 1;
  int lrow = lane & 15, lq = lane >> 4;

  f32x4 accg[4][4], accu[4][4];
#pragma unroll
  for (int a = 0; a < 4; a++)
#pragma unroll
    for (int b = 0; b < 4; b++) { accg[a][b] = (f32x4)0.f; accu[a][b] = (f32x4)0.f; }

  for (int k0 = 0; k0 < D_DIM; k0 += 32) {
#pragma unroll
    for (int rep = 0; rep < 2; rep++) {
      int idx = tid + 256 * rep;
      int row = idx >> 2, q = idx & 3;
      int ldso = (wv * 64 + 256 * rep) * 8;
      int gr = m0 + row;
      gr = (gr < Me) ? gr : (Me - 1);
      async_load16(Abuf + (size_t)(rowBase + gr) * D_DIM + k0 + q * 8, &Ash[ldso]);
      async_load16(Bge + (size_t)(n0 + row) * D_DIM + k0 + q * 8, &Bgsh[ldso]);
      async_load16(Bue + (size_t)(n0 + row) * D_DIM + k0 + q * 8, &Bush[ldso]);
    }
    __syncthreads();
    s16x8 af[4], bg[4], bu[4];
#pragma unroll
    for (int fm = 0; fm < 4; fm++)
      af[fm] = *(const s16x8*)&Ash[(mq * 64 + fm * 16 + lrow) * 32 + lq * 8];
#pragma unroll
    for (int fn = 0; fn < 4; fn++) {
      bg[fn] = *(const s16x8*)&Bgsh[(nq * 64 + fn * 16 + lrow) * 32 + lq * 8];
      bu[fn] = *(const s16x8*)&Bush[(nq * 64 + fn * 16 + lrow) * 32 + lq * 8];
    }
#pragma unroll
    for (int fm = 0; fm < 4; fm++)
#pragma unroll
      for (int fn = 0; fn < 4; fn++) {
        accg[fm][fn] = __builtin_amdgcn_mfma_f32_16x16x32_bf16(af[fm], bg[fn], accg[fm][fn], 0, 0, 0);
        accu[fm][fn] = __builtin_amdgcn_mfma_f32_16x16x32_bf16(af[fm], bu[fn], accu[fm][fn], 0, 0, 0);
      }
    __syncthreads();
  }
  // C/D layout: col=lane&15, row=(lane>>4)*4+reg
#pragma unroll
  for (int fm = 0; fm < 4; fm++) {
#pragma unroll
    for (int i = 0; i < 4; i++) {
      int m = m0 + mq * 64 + fm * 16 + lq * 4 + i;
      if (m >= Me) continue;
      size_t arow = (size_t)(rowBase + m);
#pragma unroll
      for (int fn = 0; fn < 4; fn++) {
        int col = n0 + nq * 64 + fn * 16 + lrow;
        float g = accg[fm][fn][i];
        float u = accu[fm][fn][i];
        float h = (g / (1.f + __expf(-g))) * u;
        Hbuf[arow * I_DIM + col] = f2bf(h);
      }
    }
  }
}

// ------- down GEMM: out[tok] += w * (H @ WdT), fp32 atomicAdd scatter -------
__global__ __launch_bounds__(256) void gemm_down_kernel(
    const u16* __restrict__ Abuf, const u16* __restrict__ Bd, float* __restrict__ out,
    const int* __restrict__ cnt, const int* __restrict__ offsets,
    const int* __restrict__ tlist, const float* __restrict__ wlist) {
  int e = blockIdx.z;
  int Me = cnt[e];
  int m0 = blockIdx.y * 128;
  if (m0 >= Me) return;
  int n0 = blockIdx.x * 128;
  int rowBase = offsets[e];
  const u16* Bde = Bd + (size_t)e * D_DIM * I_DIM;

  __shared__ u16 Ash[128 * 32];
  __shared__ u16 Bsh[128 * 32];

  int tid = threadIdx.x;
  int lane = tid & 63;
  int wv = tid >> 6;
  int mq = wv & 1, nq = wv >> 1;
  int lrow = lane & 15, lq = lane >> 4;

  f32x4 acc[4][4];
#pragma unroll
  for (int a = 0; a < 4; a++)
#pragma unroll
    for (int b = 0; b < 4; b++) acc[a][b] = (f32x4)0.f;

  for (int k0 = 0; k0 < I_DIM; k0 += 32) {
#pragma unroll
    for (int rep = 0; rep < 2; rep++) {
      int idx = tid + 256 * rep;
      int row = idx >> 2, q = idx & 3;
      int ldso = (wv * 64 + 256 * rep) * 8;
      int gr = m0 + row;
      gr = (gr < Me) ? gr : (Me - 1);
      async_load16(Abuf + (size_t)(rowBase + gr) * I_DIM + k0 + q * 8, &Ash[ldso]);
      async_load16(Bde + (size_t)(n0 + row) * I_DIM + k0 + q * 8, &Bsh[ldso]);
    }
    __syncthreads();
    s16x8 af[4], bfr[4];
#pragma unroll
    for (int fm = 0; fm < 4; fm++)
      af[fm] = *(const s16x8*)&Ash[(mq * 64 + fm * 16 + lrow) * 32 + lq * 8];
#pragma unroll
    for (int fn = 0; fn < 4; fn++)
      bfr[fn] = *(const s16x8*)&Bsh[(nq * 64 + fn * 16 + lrow) * 32 + lq * 8];
#pragma unroll
    for (int fm = 0; fm < 4; fm++)
#pragma unroll
      for (int fn = 0; fn < 4; fn++)
        acc[fm][fn] = __builtin_amdgcn_mfma_f32_16x16x32_bf16(af[fm], bfr[fn], acc[fm][fn], 0, 0, 0);
    __syncthreads();
  }
#pragma unroll
  for (int fm = 0; fm < 4; fm++) {
#pragma unroll
    for (int i = 0; i < 4; i++) {
      int m = m0 + mq * 64 + fm * 16 + lq * 4 + i;
      if (m >= Me) continue;
      size_t arow = (size_t)(rowBase + m);
      int tok = tlist[arow];
      float w = wlist[arow];
#pragma unroll
      for (int fn = 0; fn < 4; fn++) {
        int col = n0 + nq * 64 + fn * 16 + lrow;
        atomicAdd(&out[(size_t)tok * D_DIM + col], acc[fm][fn][i] * w);
      }
    }
  }
}

// ws layout (bytes):
//   0: cnt[16] | 64: cursor[16] | 128: probsum[16] | 192: offsets[17]
//   512: e12 | 66048: w12 | 131584: tlist | 197120: wlist
//   1 MiB: Xe bf16 [16384][1024]            (32 MiB)
//   34603008: H bf16 [16384][2816]          (88 MiB)
//   134217728: WtA bf16 [16][2816][1024]    (88 MiB)  Wg_t, later Wd_t
//   234881024: WtB bf16 [16][2816][1024]    (88 MiB)  Wu_t
//   total ~312 MiB
extern "C" void kernel_launch(void* const* d_in, const int* in_sizes, int n_in,
                              void* d_out, int out_size, void* d_ws, size_t ws_size,
                              hipStream_t stream) {
  const float* x  = (const float*)d_in[0];
  const float* gw = (const float*)d_in[1];
  const float* Wg = (const float*)d_in[2];
  const float* Wu = (const float*)d_in[3];
  const float* Wd = (const float*)d_in[4];
  float* outf = (float*)d_out;
  char* ws = (char*)d_ws;
  int*   cnt     = (int*)(ws + 0);
  int*   cursor  = (int*)(ws + 64);
  float* probsum = (float*)(ws + 128);
  int*   offsets = (int*)(ws + 192);
  int*   e12     = (int*)(ws + 512);
  float* w12     = (float*)(ws + 66048);
  int*   tlist   = (int*)(ws + 131584);
  float* wlist   = (float*)(ws + 197120);
  u16*   Xe      = (u16*)(ws + (1 << 20));
  u16*   H       = (u16*)(ws + 34603008);
  u16*   WtA     = (u16*)(ws + 134217728);
  u16*   WtB     = (u16*)(ws + 234881024);

  hipMemsetAsync(d_out, 0, (size_t)(T_TOKENS * D_DIM + 1) * sizeof(float), stream);
  hipMemsetAsync(d_ws, 0, 512, stream);

  router_kernel<<<512, 256, 0, stream>>>(x, gw, e12, w12, cnt, probsum);
  prefix_kernel<<<1, 64, 0, stream>>>(cnt, offsets, probsum, outf + (size_t)(T_TOKENS * D_DIM));
  build_kernel<<<32, 256, 0, stream>>>(e12, w12, offsets, cursor, tlist, wlist);
  gather_kernel<<<4096, 256, 0, stream>>>(x, tlist, Xe);

  // Wg: [E][1024][2816] -> WtA [E][2816][1024];  Wu -> WtB
  transpose_kernel<D_DIM, I_DIM><<<dim3(16, 44, E_NUM), 256, 0, stream>>>(Wg, WtA);
  transpose_kernel<D_DIM, I_DIM><<<dim3(16, 44, E_NUM), 256, 0, stream>>>(Wu, WtB);

  gemm_gu_kernel<<<dim3(22, 64, E_NUM), 256, 0, stream>>>(Xe, WtA, WtB, H, cnt, offsets);

  // Wd: [E][2816][1024] -> WtA [E][1024][2816]
  transpose_kernel<I_DIM, D_DIM><<<dim3(44, 16, E_NUM), 256, 0, stream>>>(Wd, WtA);

  gemm_down_kernel<<<dim3(8, 64, E_NUM), 256, 0, stream>>>(H, WtA, outf, cnt, offsets, tlist, wlist);
}